// Round 6
// baseline (10699.258 us; speedup 1.0000x reference)
//
#include <hip/hip_runtime.h>
#include <hip/hip_bf16.h>
#include <math.h>

#define SEQ   16384
#define DDIM  4096
#define NH    32
#define DH    128
#define RLAT  64

using u16 = unsigned short;
typedef __attribute__((ext_vector_type(8))) short short8;
typedef __attribute__((ext_vector_type(4))) float f32x4;

__device__ __forceinline__ u16 f2bf(float x) {
  __hip_bfloat16 b = __float2bfloat16(x);
  return *reinterpret_cast<u16*>(&b);
}
__device__ __forceinline__ float bf2f(u16 u) {
  __hip_bfloat16 b;
  *reinterpret_cast<u16*>(&b) = u;
  return __bfloat162float(b);
}

// ---------------------------------------------------------------------------
// Split-bf16 GEMM: C = A @ B, A [16384][4096] as (Ah,Al) bf16 pair row-major,
// B supplied TRANSPOSED [N][K] as (Bh,Bl) bf16 pair row-major.
// acc += Ah*Bh + Ah*Bl + Al*Bh  (fp32 MFMA accumulation) ~ fp32 precision.
// 128x128 tile, BK=32, 4 waves (2x2), 4x4 16x16x32 frags/wave, 3 MFMA each.
// Block order: bm SLOW / bn FAST (32 consecutive bids = 1 A-panel x all 32
// B-panels) so concurrent working set (A-window ~48MB + B 64MB) fits L3:
// A read ~once, B stays L3-resident.  (Round-4 slab order caused 7.5GB/GEMM.)
// EPI: 0 = Cf = acc*scale (fp32)
//      1 = (Ch,Cl) pair
//      2 = (Ch,Cl) pair of gelu_erf(acc + bias)
//      3 = Cf = acc + bias + (Rh+Rl)   (final, fp32)
// ---------------------------------------------------------------------------
template <int EPI>
__global__ __launch_bounds__(256, 3) void gemm_split(
    const u16* __restrict__ Ah, const u16* __restrict__ Al,
    const u16* __restrict__ Bh, const u16* __restrict__ Bl,
    float* __restrict__ Cf, u16* __restrict__ Ch, u16* __restrict__ Cl,
    const float* __restrict__ bias, const u16* __restrict__ Rh,
    const u16* __restrict__ Rl, float scale) {
  __shared__ __align__(16) u16 smem[4 * 4096];  // Ah | Al | Bh | Bl tiles (32 KB)

  const int tid = threadIdx.x;
  const int lane = tid & 63;
  const int wave = tid >> 6;
  const int wm = wave >> 1, wn = wave & 1;

  // bm slow, bn fast; bn grouped per-XCD (bid&7) for L2 locality. Bijective.
  const int bid = blockIdx.x;
  const int bm = (bid >> 5) * 128;                            // 128 m-panels, slow
  const int bn = (((bid & 7) << 2) | ((bid >> 3) & 3)) * 128; // 32 n-panels, fast

  // --- staging constants: wave w stages tile w; lane covers (row=l>>2, slot=l&3)
  // LDS linear dest (row, slot) holds global k-block = slot ^ ((row>>1)&3).
  const int kblk_st = (lane & 3) ^ ((lane >> 3) & 3);
  const u16* mat = (wave == 0) ? Ah : (wave == 1) ? Al : (wave == 2) ? Bh : Bl;
  const int rowbase = (wave < 2) ? bm : bn;
  const u16* gbase = mat + (size_t)(rowbase + (lane >> 2)) * DDIM + kblk_st * 8;
  u16* ldst = smem + wave * 4096;

  // --- read constants: frag row = base + (lane&15), kblock = lane>>4
  const int r15 = lane & 15;
  const int kb = lane >> 4;
  const int slot = kb ^ ((r15 >> 1) & 3);   // inverse of staging XOR
  const int aoff = (wm * 64 + r15) * 32 + slot * 8;  // + mi*512
  const int boff = (wn * 64 + r15) * 32 + slot * 8;  // + ni*512
  const u16* As_h = smem;
  const u16* As_l = smem + 4096;
  const u16* Bs_h = smem + 8192;
  const u16* Bs_l = smem + 12288;

  f32x4 acc[4][4];
#pragma unroll
  for (int i = 0; i < 4; ++i)
#pragma unroll
    for (int j = 0; j < 4; ++j) acc[i][j] = (f32x4){0.f, 0.f, 0.f, 0.f};

  for (int k0 = 0; k0 < DDIM; k0 += 32) {
    // stage this K-step's 4 tiles (8 x 1KB chunks per wave)
#pragma unroll
    for (int c = 0; c < 8; ++c) {
      __builtin_amdgcn_global_load_lds(
          (const __attribute__((address_space(1))) unsigned int*)(gbase + (size_t)c * 16 * DDIM + k0),
          (__attribute__((address_space(3))) unsigned int*)(ldst + c * 512),
          16, 0, 0);
    }
    __syncthreads();  // vmcnt(0) drain + barrier: tiles ready

    short8 ah[4], al[4], bh[4], bl[4];
#pragma unroll
    for (int i = 0; i < 4; ++i) {
      ah[i] = *(const short8*)(As_h + aoff + i * 512);
      al[i] = *(const short8*)(As_l + aoff + i * 512);
      bh[i] = *(const short8*)(Bs_h + boff + i * 512);
      bl[i] = *(const short8*)(Bs_l + boff + i * 512);
    }
#pragma unroll
    for (int mi = 0; mi < 4; ++mi)
#pragma unroll
      for (int ni = 0; ni < 4; ++ni) {
        acc[mi][ni] = __builtin_amdgcn_mfma_f32_16x16x32_bf16(ah[mi], bh[ni], acc[mi][ni], 0, 0, 0);
        acc[mi][ni] = __builtin_amdgcn_mfma_f32_16x16x32_bf16(ah[mi], bl[ni], acc[mi][ni], 0, 0, 0);
        acc[mi][ni] = __builtin_amdgcn_mfma_f32_16x16x32_bf16(al[mi], bh[ni], acc[mi][ni], 0, 0, 0);
      }
    __syncthreads();  // all reads done before next stage overwrites
  }

  // epilogue: D lane map (verified m89): col = lane&15, row = (lane>>4)*4 + q
  const int orow = bm + wm * 64 + kb * 4;
  const int ocol = bn + wn * 64 + r15;
#pragma unroll
  for (int mi = 0; mi < 4; ++mi)
#pragma unroll
    for (int ni = 0; ni < 4; ++ni)
#pragma unroll
      for (int q = 0; q < 4; ++q) {
        const size_t row = (size_t)(orow + mi * 16 + q);
        const size_t col = (size_t)(ocol + ni * 16);
        const size_t o = row * DDIM + col;
        float v = acc[mi][ni][q];
        if (EPI == 0) {
          Cf[o] = v * scale;
        } else if (EPI == 1) {
          u16 h = f2bf(v);
          Ch[o] = h;
          Cl[o] = f2bf(v - bf2f(h));
        } else if (EPI == 2) {
          v += bias[col];
          v = 0.5f * v * (1.0f + erff(v * 0.70710678118654752f));
          u16 h = f2bf(v);
          Ch[o] = h;
          Cl[o] = f2bf(v - bf2f(h));
        } else {
          v += bias[col] + bf2f(Rh[o]) + bf2f(Rl[o]);
          Cf[o] = v;
        }
      }
}

// ---------------------------------------------------------------------------
// Latent attention, fp32 in (xq), bf16-pair out. grid (SEQ/64, NH), 4 waves.
// ---------------------------------------------------------------------------
__global__ __launch_bounds__(256) void attn_k(const float* __restrict__ xq,
                                              const float* __restrict__ kvl,
                                              u16* __restrict__ oh,
                                              u16* __restrict__ ol) {
  __shared__ float kv_s[RLAT * 129];
  __shared__ float xrow[4][DH];
  __shared__ float pbuf[4][RLAT];

  const int h = blockIdx.y;
  const int s0 = blockIdx.x * 64;
  const int tid = threadIdx.x;

#pragma unroll
  for (int i = 0; i < 32; ++i) {
    int idx = i * 256 + tid;
    int r = idx >> 7, d = idx & 127;
    kv_s[r * 129 + d] = kvl[(size_t)r * DDIM + h * DH + d];
  }
  __syncthreads();

  const int wave = tid >> 6;
  const int lane = tid & 63;

  for (int it = 0; it < 16; ++it) {
    const int s = s0 + wave * 16 + it;
    const size_t base = (size_t)s * DDIM + h * DH;
    xrow[wave][lane] = xq[base + lane];
    xrow[wave][lane + 64] = xq[base + lane + 64];

    float sc = 0.f;
    const float* kr = &kv_s[lane * 129];
#pragma unroll 8
    for (int d = 0; d < DH; ++d) sc = fmaf(xrow[wave][d], kr[d], sc);

    float mx = sc;
#pragma unroll
    for (int off = 32; off; off >>= 1) mx = fmaxf(mx, __shfl_xor(mx, off));
    float p = expf(sc - mx);
    float sm = p;
#pragma unroll
    for (int off = 32; off; off >>= 1) sm += __shfl_xor(sm, off);
    p /= sm;
    pbuf[wave][lane] = p;

    float a0 = 0.f, a1 = 0.f;
#pragma unroll 8
    for (int r = 0; r < RLAT; ++r) {
      float pv = pbuf[wave][r];
      a0 = fmaf(pv, kv_s[r * 129 + lane], a0);
      a1 = fmaf(pv, kv_s[r * 129 + lane + 64], a1);
    }
    u16 h0 = f2bf(a0);
    oh[base + lane] = h0;
    ol[base + lane] = f2bf(a0 - bf2f(h0));
    u16 h1 = f2bf(a1);
    oh[base + lane + 64] = h1;
    ol[base + lane + 64] = f2bf(a1 - bf2f(h1));
  }
}

// ---------------------------------------------------------------------------
// fp32 -> (hi,lo) bf16 pair, elementwise (for query)
// ---------------------------------------------------------------------------
__global__ __launch_bounds__(256) void conv_split(const float* __restrict__ in,
                                                  u16* __restrict__ oh,
                                                  u16* __restrict__ ol,
                                                  long n4) {
  long i = (long)blockIdx.x * blockDim.x + threadIdx.x;
  const long stride = (long)gridDim.x * blockDim.x;
  for (; i < n4; i += stride) {
    float4 v = ((const float4*)in)[i];
    u16 h0 = f2bf(v.x), h1 = f2bf(v.y), h2 = f2bf(v.z), h3 = f2bf(v.w);
    u16 l0 = f2bf(v.x - bf2f(h0)), l1 = f2bf(v.y - bf2f(h1));
    u16 l2 = f2bf(v.z - bf2f(h2)), l3 = f2bf(v.w - bf2f(h3));
    uint2 hp, lp;
    hp.x = (uint)h0 | ((uint)h1 << 16);
    hp.y = (uint)h2 | ((uint)h3 << 16);
    lp.x = (uint)l0 | ((uint)l1 << 16);
    lp.y = (uint)l2 | ((uint)l3 << 16);
    ((uint2*)oh)[i] = hp;
    ((uint2*)ol)[i] = lp;
  }
}

// ---------------------------------------------------------------------------
// weight fp32 [K][N] -> transposed bf16 pair [N][K]. 64x64 tiles, grid 4096.
// ---------------------------------------------------------------------------
__global__ __launch_bounds__(256) void conv_wT(const float* __restrict__ w,
                                               u16* __restrict__ oh,
                                               u16* __restrict__ ol) {
  __shared__ float t[64][65];
  const int kb = blockIdx.x & 63, nb = blockIdx.x >> 6;
  const int tid = threadIdx.x;
#pragma unroll
  for (int j = 0; j < 16; ++j) {
    int idx = j * 256 + tid;
    int r = idx >> 6, c = idx & 63;
    t[r][c] = w[(size_t)(kb * 64 + r) * DDIM + nb * 64 + c];
  }
  __syncthreads();
#pragma unroll
  for (int j = 0; j < 16; ++j) {
    int idx = j * 256 + tid;
    int r = idx >> 6, c = idx & 63;  // out: row = n, col = k
    float v = t[c][r];
    u16 h = f2bf(v);
    size_t o = (size_t)(nb * 64 + r) * DDIM + kb * 64 + c;
    oh[o] = h;
    ol[o] = f2bf(v - bf2f(h));
  }
}

extern "C" void kernel_launch(void* const* d_in, const int* in_sizes, int n_in,
                              void* d_out, int out_size, void* d_ws, size_t ws_size,
                              hipStream_t stream) {
  const float* query = (const float*)d_in[0];
  const float* kvl   = (const float*)d_in[1];
  const float* wq    = (const float*)d_in[2];
  const float* wo    = (const float*)d_in[3];
  const float* w1    = (const float*)d_in[4];
  const float* b1    = (const float*)d_in[5];
  const float* w2    = (const float*)d_in[6];
  const float* b2    = (const float*)d_in[7];
  float* out = (float*)d_out;

  char* ws = (char*)d_ws;
  const size_t HB = (size_t)SEQ * DDIM * sizeof(u16);  // 128 MB (one bf16 act matrix)
  const size_t WB = (size_t)DDIM * DDIM * sizeof(u16); // 32 MB  (one bf16 weight)

  // R0 (256MB): q pair -> attn-out pair -> h pair
  u16* qh  = (u16*)(ws);
  u16* ql  = (u16*)(ws + HB);
  u16* ath = qh;  u16* atl = ql;   // after GEMM1
  u16* hh  = qh;  u16* hl  = ql;   // after GEMM2/3
  // R1 (256MB): xq fp32 -> out2 pair
  float* xqf = (float*)(ws + 2 * HB);
  u16* o2h = (u16*)(ws + 2 * HB);
  u16* o2l = (u16*)(ws + 3 * HB);
  // R2 (256MB): weight pairs (transposed)
  char* wr = ws + 4 * HB;
  u16* wqh = (u16*)(wr + 0 * WB); u16* wql = (u16*)(wr + 1 * WB);
  u16* woh = (u16*)(wr + 2 * WB); u16* wol = (u16*)(wr + 3 * WB);
  u16* w1h = (u16*)(wr + 4 * WB); u16* w1l = (u16*)(wr + 5 * WB);
  u16* w2h = (u16*)(wr + 6 * WB); u16* w2l = (u16*)(wr + 7 * WB);

  const long n4 = (long)SEQ * DDIM / 4;
  conv_split<<<8192, 256, 0, stream>>>(query, qh, ql, n4);
  conv_wT<<<4096, 256, 0, stream>>>(wq, wqh, wql);
  conv_wT<<<4096, 256, 0, stream>>>(wo, woh, wol);
  conv_wT<<<4096, 256, 0, stream>>>(w1, w1h, w1l);
  conv_wT<<<4096, 256, 0, stream>>>(w2, w2h, w2l);

  const dim3 gg(4096), gb(256);
  // xq = (q @ wq) * R^-0.5   (fp32 out for attention)
  gemm_split<0><<<gg, gb, 0, stream>>>(qh, ql, wqh, wql, xqf, nullptr, nullptr,
                                       nullptr, nullptr, nullptr, 0.125f);
  // attention -> pair
  attn_k<<<dim3(SEQ / 64, NH), 256, 0, stream>>>(xqf, kvl, ath, atl);
  // out2 = attn @ wo -> pair only (residual reconstructed later as hi+lo)
  gemm_split<1><<<gg, gb, 0, stream>>>(ath, atl, woh, wol, nullptr, o2h, o2l,
                                       nullptr, nullptr, nullptr, 1.f);
  // h = gelu(out2 @ w1 + b1) -> pair
  gemm_split<2><<<gg, gb, 0, stream>>>(o2h, o2l, w1h, w1l, nullptr, hh, hl,
                                       b1, nullptr, nullptr, 1.f);
  // out = h @ w2 + b2 + out2   (fp32)
  gemm_split<3><<<gg, gb, 0, stream>>>(hh, hl, w2h, w2l, out, nullptr, nullptr,
                                       b2, o2h, o2l, 1.f);
}

// Round 9
// 7721.362 us; speedup vs baseline: 1.3857x; 1.3857x over previous
//
#include <hip/hip_runtime.h>
#include <hip/hip_bf16.h>
#include <math.h>

#define SEQ   16384
#define DDIM  4096
#define NH    32
#define DH    128
#define RLAT  64

using u16 = unsigned short;
typedef __attribute__((ext_vector_type(8))) short short8;
typedef __attribute__((ext_vector_type(4))) float f32x4;

__device__ __forceinline__ u16 f2bf(float x) {
  __hip_bfloat16 b = __float2bfloat16(x);
  return *reinterpret_cast<u16*>(&b);
}
__device__ __forceinline__ float bf2f(u16 u) {
  __hip_bfloat16 b;
  *reinterpret_cast<u16*>(&b) = u;
  return __bfloat162float(b);
}

#define GLD16(gp, lp)                                                        \
  __builtin_amdgcn_global_load_lds(                                          \
      (const __attribute__((address_space(1))) unsigned int*)(gp),           \
      (__attribute__((address_space(3))) unsigned int*)(lp), 16, 0, 0)

// ---------------------------------------------------------------------------
// Split-bf16 GEMM, 256x256 tile, 512 thr (8 waves 2Mx4N), BK=32 pair-packed.
// A [16384][4096] as (Ah,Al) bf16 row-major; B TRANSPOSED [N][K] as (Bh,Bl).
// acc += Ah*Bh + Ah*Bl + Al*Bh (fp32 MFMA).  Per wave: 128x64 out = 8x4 frags.
// LDS: 2 x 64KB tiles (Ah|Al|Bh|Bl each [256][32] bf16). Strict double-buffer:
// all 8 stage-issues for tile t+1 at phase 0 of tile t (~3 phases of slack so
// the boundary vmcnt(0) is free); raw s_barrier (no implicit vmcnt drain);
// 4 phases/tile: {12 ds_read_b128 quad, barrier, prio1, 24 MFMA, prio0,
// barrier}.  Slot-XOR swizzle (verified 0 bank conflicts) on global source,
// inverted on ds_read (involution, rule 21).
// EPI: 0 Cf=acc*scale | 1 (Ch,Cl) | 2 (Ch,Cl)=gelu(acc+bias) | 3 Cf=acc+bias+R
// ---------------------------------------------------------------------------
template <int EPI>
__global__ __launch_bounds__(512, 2) void gemm_split(
    const u16* __restrict__ Ah, const u16* __restrict__ Al,
    const u16* __restrict__ Bh, const u16* __restrict__ Bl,
    float* __restrict__ Cf, u16* __restrict__ Ch, u16* __restrict__ Cl,
    const float* __restrict__ bias, const u16* __restrict__ Rh,
    const u16* __restrict__ Rl, float scale) {
  __shared__ __align__(16) u16 smem[2][4][8192];  // [dbuf][Ah|Al|Bh|Bl][256*32]

  const int tid = threadIdx.x;
  const int lane = tid & 63;
  const int w = tid >> 6;            // 0..7
  const int wm = w >> 2, wn = w & 3; // 2 x 4 wave grid

  // XCD-chunked, bm slow within chunk: 16 same-A-panel blocks co-resident/XCD
  const int bid = blockIdx.x;                 // 1024 blocks
  const int wg = (bid & 7) * 128 + (bid >> 3);
  const int bm = (wg >> 4) * 256;             // 64 m-panels
  const int bn = (wg & 15) * 256;             // 16 n-panels

  // --- staging: thread covers (row = w*16 + lane>>2 [+128c], slot = lane&3)
  // global k-block = slot ^ ((row>>1)&3) = (lane&3) ^ ((lane>>3)&3)
  const int kblk = (lane & 3) ^ ((lane >> 3) & 3);
  const int grow = w * 16 + (lane >> 2);
  const u16* gAh = Ah + (size_t)(bm + grow) * DDIM + kblk * 8;
  const u16* gAl = Al + (size_t)(bm + grow) * DDIM + kblk * 8;
  const u16* gBh = Bh + (size_t)(bn + grow) * DDIM + kblk * 8;
  const u16* gBl = Bl + (size_t)(bn + grow) * DDIM + kblk * 8;
  const int ldso = w * 16 * 32;  // wave-uniform LDS base (u16), + c*128*32

  // --- reads: frag row base + r15, k-slot kb; phys slot = kb ^ ((r15>>1)&3)
  const int r15 = lane & 15, kb = lane >> 4;
  const int sphys = (kb ^ ((r15 >> 1) & 3)) * 8;

  f32x4 acc[8][4] = {};

  // prologue: stage tile 0 into buf 0
#pragma unroll
  for (int c = 0; c < 2; ++c) {
    const size_t go = (size_t)c * 128 * DDIM;
    const int lo = ldso + c * 128 * 32;
    GLD16(gAh + go, &smem[0][0][lo]);
    GLD16(gAl + go, &smem[0][1][lo]);
    GLD16(gBh + go, &smem[0][2][lo]);
    GLD16(gBl + go, &smem[0][3][lo]);
  }
  asm volatile("s_waitcnt vmcnt(0)" ::: "memory");
  __builtin_amdgcn_s_barrier();

  for (int t = 0; t < 128; ++t) {
    const u16* br = &smem[t & 1][0][0];
    u16* bw = &smem[(t + 1) & 1][0][0];
    const int k0n = (t + 1) * 32;
#pragma unroll
    for (int p = 0; p < 4; ++p) {
      if (p == 0 && t < 127) {  // stage tile t+1 (uniform branch)
#pragma unroll
        for (int c = 0; c < 2; ++c) {
          const size_t go = (size_t)c * 128 * DDIM + k0n;
          const int lo = ldso + c * 128 * 32;
          GLD16(gAh + go, bw + 0 * 8192 + lo);
          GLD16(gAl + go, bw + 1 * 8192 + lo);
          GLD16(gBh + go, bw + 2 * 8192 + lo);
          GLD16(gBl + go, bw + 3 * 8192 + lo);
        }
      }
      short8 xah[4], xal[4], xbh[2], xbl[2];
#pragma unroll
      for (int mi = 0; mi < 4; ++mi) {
        const int row = wm * 128 + (p & 1) * 64 + mi * 16 + r15;
        xah[mi] = *(const short8*)(br + 0 * 8192 + row * 32 + sphys);
        xal[mi] = *(const short8*)(br + 1 * 8192 + row * 32 + sphys);
      }
#pragma unroll
      for (int ni = 0; ni < 2; ++ni) {
        const int row = wn * 64 + (p >> 1) * 32 + ni * 16 + r15;
        xbh[ni] = *(const short8*)(br + 2 * 8192 + row * 32 + sphys);
        xbl[ni] = *(const short8*)(br + 3 * 8192 + row * 32 + sphys);
      }
      __builtin_amdgcn_s_barrier();
      __builtin_amdgcn_s_setprio(1);
#pragma unroll
      for (int mi = 0; mi < 4; ++mi)
#pragma unroll
        for (int ni = 0; ni < 2; ++ni) {
          f32x4& a = acc[(p & 1) * 4 + mi][(p >> 1) * 2 + ni];
          a = __builtin_amdgcn_mfma_f32_16x16x32_bf16(xah[mi], xbh[ni], a, 0, 0, 0);
          a = __builtin_amdgcn_mfma_f32_16x16x32_bf16(xah[mi], xbl[ni], a, 0, 0, 0);
          a = __builtin_amdgcn_mfma_f32_16x16x32_bf16(xal[mi], xbh[ni], a, 0, 0, 0);
        }
      __builtin_amdgcn_s_setprio(0);
      __builtin_amdgcn_s_barrier();
    }
    asm volatile("s_waitcnt vmcnt(0)" ::: "memory");  // tile t+1 landed
    __builtin_amdgcn_s_barrier();
  }

  // epilogue: D map (m89): col = lane&15, row = (lane>>4)*4 + q
  const int orow = bm + wm * 128 + kb * 4;
  const int ocol = bn + wn * 64 + r15;
#pragma unroll
  for (int mi = 0; mi < 8; ++mi)
#pragma unroll
    for (int ni = 0; ni < 4; ++ni)
#pragma unroll
      for (int q = 0; q < 4; ++q) {
        const size_t row = (size_t)(orow + mi * 16 + q);
        const size_t col = (size_t)(ocol + ni * 16);
        const size_t o = row * DDIM + col;
        float v = acc[mi][ni][q];
        if (EPI == 0) {
          Cf[o] = v * scale;
        } else if (EPI == 1) {
          u16 h = f2bf(v);
          Ch[o] = h;
          Cl[o] = f2bf(v - bf2f(h));
        } else if (EPI == 2) {
          v += bias[col];
          v = 0.5f * v * (1.0f + erff(v * 0.70710678118654752f));
          u16 h = f2bf(v);
          Ch[o] = h;
          Cl[o] = f2bf(v - bf2f(h));
        } else {
          v += bias[col] + bf2f(Rh[o]) + bf2f(Rl[o]);
          Cf[o] = v;
        }
      }
}

// ---------------------------------------------------------------------------
// Latent attention, fp32 in (xq), bf16-pair out. grid (SEQ/64, NH), 4 waves.
// ---------------------------------------------------------------------------
__global__ __launch_bounds__(256) void attn_k(const float* __restrict__ xq,
                                              const float* __restrict__ kvl,
                                              u16* __restrict__ oh,
                                              u16* __restrict__ ol) {
  __shared__ float kv_s[RLAT * 129];
  __shared__ float xrow[4][DH];
  __shared__ float pbuf[4][RLAT];

  const int h = blockIdx.y;
  const int s0 = blockIdx.x * 64;
  const int tid = threadIdx.x;

#pragma unroll
  for (int i = 0; i < 32; ++i) {
    int idx = i * 256 + tid;
    int r = idx >> 7, d = idx & 127;
    kv_s[r * 129 + d] = kvl[(size_t)r * DDIM + h * DH + d];
  }
  __syncthreads();

  const int wave = tid >> 6;
  const int lane = tid & 63;

  for (int it = 0; it < 16; ++it) {
    const int s = s0 + wave * 16 + it;
    const size_t base = (size_t)s * DDIM + h * DH;
    xrow[wave][lane] = xq[base + lane];
    xrow[wave][lane + 64] = xq[base + lane + 64];

    float sc = 0.f;
    const float* kr = &kv_s[lane * 129];
#pragma unroll 8
    for (int d = 0; d < DH; ++d) sc = fmaf(xrow[wave][d], kr[d], sc);

    float mx = sc;
#pragma unroll
    for (int off = 32; off; off >>= 1) mx = fmaxf(mx, __shfl_xor(mx, off));
    float p = expf(sc - mx);
    float sm = p;
#pragma unroll
    for (int off = 32; off; off >>= 1) sm += __shfl_xor(sm, off);
    p /= sm;
    pbuf[wave][lane] = p;

    float a0 = 0.f, a1 = 0.f;
#pragma unroll 8
    for (int r = 0; r < RLAT; ++r) {
      float pv = pbuf[wave][r];
      a0 = fmaf(pv, kv_s[r * 129 + lane], a0);
      a1 = fmaf(pv, kv_s[r * 129 + lane + 64], a1);
    }
    u16 h0 = f2bf(a0);
    oh[base + lane] = h0;
    ol[base + lane] = f2bf(a0 - bf2f(h0));
    u16 h1 = f2bf(a1);
    oh[base + lane + 64] = h1;
    ol[base + lane + 64] = f2bf(a1 - bf2f(h1));
  }
}

// ---------------------------------------------------------------------------
// fp32 -> (hi,lo) bf16 pair, elementwise (for query)
// ---------------------------------------------------------------------------
__global__ __launch_bounds__(256) void conv_split(const float* __restrict__ in,
                                                  u16* __restrict__ oh,
                                                  u16* __restrict__ ol,
                                                  long n4) {
  long i = (long)blockIdx.x * blockDim.x + threadIdx.x;
  const long stride = (long)gridDim.x * blockDim.x;
  for (; i < n4; i += stride) {
    float4 v = ((const float4*)in)[i];
    u16 h0 = f2bf(v.x), h1 = f2bf(v.y), h2 = f2bf(v.z), h3 = f2bf(v.w);
    u16 l0 = f2bf(v.x - bf2f(h0)), l1 = f2bf(v.y - bf2f(h1));
    u16 l2 = f2bf(v.z - bf2f(h2)), l3 = f2bf(v.w - bf2f(h3));
    uint2 hp, lp;
    hp.x = (uint)h0 | ((uint)h1 << 16);
    hp.y = (uint)h2 | ((uint)h3 << 16);
    lp.x = (uint)l0 | ((uint)l1 << 16);
    lp.y = (uint)l2 | ((uint)l3 << 16);
    ((uint2*)oh)[i] = hp;
    ((uint2*)ol)[i] = lp;
  }
}

// ---------------------------------------------------------------------------
// weight fp32 [K][N] -> transposed bf16 pair [N][K]. 64x64 tiles, grid 4096.
// ---------------------------------------------------------------------------
__global__ __launch_bounds__(256) void conv_wT(const float* __restrict__ w,
                                               u16* __restrict__ oh,
                                               u16* __restrict__ ol) {
  __shared__ float t[64][65];
  const int kb = blockIdx.x & 63, nb = blockIdx.x >> 6;
  const int tid = threadIdx.x;
#pragma unroll
  for (int j = 0; j < 16; ++j) {
    int idx = j * 256 + tid;
    int r = idx >> 6, c = idx & 63;
    t[r][c] = w[(size_t)(kb * 64 + r) * DDIM + nb * 64 + c];
  }
  __syncthreads();
#pragma unroll
  for (int j = 0; j < 16; ++j) {
    int idx = j * 256 + tid;
    int r = idx >> 6, c = idx & 63;  // out: row = n, col = k
    float v = t[c][r];
    u16 h = f2bf(v);
    size_t o = (size_t)(nb * 64 + r) * DDIM + kb * 64 + c;
    oh[o] = h;
    ol[o] = f2bf(v - bf2f(h));
  }
}

extern "C" void kernel_launch(void* const* d_in, const int* in_sizes, int n_in,
                              void* d_out, int out_size, void* d_ws, size_t ws_size,
                              hipStream_t stream) {
  const float* query = (const float*)d_in[0];
  const float* kvl   = (const float*)d_in[1];
  const float* wq    = (const float*)d_in[2];
  const float* wo    = (const float*)d_in[3];
  const float* w1    = (const float*)d_in[4];
  const float* b1    = (const float*)d_in[5];
  const float* w2    = (const float*)d_in[6];
  const float* b2    = (const float*)d_in[7];
  float* out = (float*)d_out;

  char* ws = (char*)d_ws;
  const size_t HB = (size_t)SEQ * DDIM * sizeof(u16);  // 128 MB (one bf16 act matrix)
  const size_t WB = (size_t)DDIM * DDIM * sizeof(u16); // 32 MB  (one bf16 weight)

  // R0 (256MB): q pair -> attn-out pair -> h pair
  u16* qh  = (u16*)(ws);
  u16* ql  = (u16*)(ws + HB);
  u16* ath = qh;  u16* atl = ql;   // after GEMM1
  u16* hh  = qh;  u16* hl  = ql;   // after GEMM2/3
  // R1 (256MB): xq fp32 -> out2 pair
  float* xqf = (float*)(ws + 2 * HB);
  u16* o2h = (u16*)(ws + 2 * HB);
  u16* o2l = (u16*)(ws + 3 * HB);
  // R2 (256MB): weight pairs (transposed)
  char* wr = ws + 4 * HB;
  u16* wqh = (u16*)(wr + 0 * WB); u16* wql = (u16*)(wr + 1 * WB);
  u16* woh = (u16*)(wr + 2 * WB); u16* wol = (u16*)(wr + 3 * WB);
  u16* w1h = (u16*)(wr + 4 * WB); u16* w1l = (u16*)(wr + 5 * WB);
  u16* w2h = (u16*)(wr + 6 * WB); u16* w2l = (u16*)(wr + 7 * WB);

  const long n4 = (long)SEQ * DDIM / 4;
  conv_split<<<8192, 256, 0, stream>>>(query, qh, ql, n4);
  conv_wT<<<4096, 256, 0, stream>>>(wq, wqh, wql);
  conv_wT<<<4096, 256, 0, stream>>>(wo, woh, wol);
  conv_wT<<<4096, 256, 0, stream>>>(w1, w1h, w1l);
  conv_wT<<<4096, 256, 0, stream>>>(w2, w2h, w2l);

  const dim3 gg(1024), gb(512);  // 64 x 16 panels of 256x256
  // xq = (q @ wq) * R^-0.5   (fp32 out for attention)
  gemm_split<0><<<gg, gb, 0, stream>>>(qh, ql, wqh, wql, xqf, nullptr, nullptr,
                                       nullptr, nullptr, nullptr, 0.125f);
  // attention -> pair
  attn_k<<<dim3(SEQ / 64, NH), 256, 0, stream>>>(xqf, kvl, ath, atl);
  // out2 = attn @ wo -> pair only (residual reconstructed later as hi+lo)
  gemm_split<1><<<gg, gb, 0, stream>>>(ath, atl, woh, wol, nullptr, o2h, o2l,
                                       nullptr, nullptr, nullptr, 1.f);
  // h = gelu(out2 @ w1 + b1) -> pair
  gemm_split<2><<<gg, gb, 0, stream>>>(o2h, o2l, w1h, w1l, nullptr, hh, hl,
                                       b1, nullptr, nullptr, 1.f);
  // out = h @ w2 + b2 + out2   (fp32)
  gemm_split<3><<<gg, gb, 0, stream>>>(hh, hl, w2h, w2l, out, nullptr, nullptr,
                                       b2, o2h, o2l, 1.f);
}

// Round 10
// 6575.558 us; speedup vs baseline: 1.6271x; 1.1743x over previous
//
#include <hip/hip_runtime.h>
#include <hip/hip_bf16.h>
#include <math.h>

#define SEQ   16384
#define DDIM  4096
#define NH    32
#define DH    128
#define RLAT  64

using u16 = unsigned short;
typedef __attribute__((ext_vector_type(8))) short short8;
typedef __attribute__((ext_vector_type(4))) float f32x4;

__device__ __forceinline__ u16 f2bf(float x) {
  __hip_bfloat16 b = __float2bfloat16(x);
  return *reinterpret_cast<u16*>(&b);
}
__device__ __forceinline__ float bf2f(u16 u) {
  __hip_bfloat16 b;
  *reinterpret_cast<u16*>(&b) = u;
  return __bfloat162float(b);
}

#define GLD16(gp, lp)                                                        \
  __builtin_amdgcn_global_load_lds(                                          \
      (const __attribute__((address_space(1))) unsigned int*)(gp),           \
      (__attribute__((address_space(3))) unsigned int*)(lp), 16, 0, 0)

// ---------------------------------------------------------------------------
// Split-bf16 GEMM, 256x256 tile, 512 thr (8 waves 2Mx4N), BK=32 pair-packed.
// A [16384][4096] as (Ah,Al) bf16 row-major; B TRANSPOSED [N][K] as (Bh,Bl).
// acc += Ah*Bh + Ah*Bl + Al*Bh (fp32 MFMA).  Per wave: 128x64 out = 8x4 frags.
// LDS: 2 x 64KB double-buffer. Staging for tile t+1 issues at top of tile t;
// only sync = tile-boundary vmcnt(0)+s_barrier (own-loads drain + collective
// barrier => all staging landed; ds_reads are register-consumed by MFMAs
// before any wave reaches the barrier, so the to-be-overwritten buffer is
// quiescent).  NO mid-tile barriers: waves desync so LDS-read pipe overlaps
// MFMA pipe across waves (m114).  Fragment re-read amplification cut: A-frags
// read ONCE per tile (2 m-halves of 4), B rolling-prefetched per half
// (256 KB LDS/tile vs 384 in the 4-phase version).  Slot-XOR swizzle
// (measured 0 bank conflicts) on global source, inverted on ds_read.
// EPI: 0 Cf=acc*scale | 1 (Ch,Cl) | 2 (Ch,Cl)=gelu(acc+bias) | 3 Cf=acc+bias+R
// ---------------------------------------------------------------------------
template <int EPI>
__global__ __launch_bounds__(512, 2) void gemm_split(
    const u16* __restrict__ Ah, const u16* __restrict__ Al,
    const u16* __restrict__ Bh, const u16* __restrict__ Bl,
    float* __restrict__ Cf, u16* __restrict__ Ch, u16* __restrict__ Cl,
    const float* __restrict__ bias, const u16* __restrict__ Rh,
    const u16* __restrict__ Rl, float scale) {
  __shared__ __align__(16) u16 smem[2][4][8192];  // [dbuf][Ah|Al|Bh|Bl][256*32]

  const int tid = threadIdx.x;
  const int lane = tid & 63;
  const int w = tid >> 6;            // 0..7
  const int wm = w >> 2, wn = w & 3; // 2 x 4 wave grid

  // XCD-chunked, bm slow within chunk: 16 same-A-panel blocks co-resident/XCD
  const int bid = blockIdx.x;                 // 1024 blocks
  const int wg = (bid & 7) * 128 + (bid >> 3);
  const int bm = (wg >> 4) * 256;             // 64 m-panels
  const int bn = (wg & 15) * 256;             // 16 n-panels

  // --- staging: thread covers (row = w*16 + lane>>2 [+128c], slot = lane&3)
  // global k-block = slot ^ ((row>>1)&3) = (lane&3) ^ ((lane>>3)&3)
  const int kblk = (lane & 3) ^ ((lane >> 3) & 3);
  const int grow = w * 16 + (lane >> 2);
  const u16* gAh = Ah + (size_t)(bm + grow) * DDIM + kblk * 8;
  const u16* gAl = Al + (size_t)(bm + grow) * DDIM + kblk * 8;
  const u16* gBh = Bh + (size_t)(bn + grow) * DDIM + kblk * 8;
  const u16* gBl = Bl + (size_t)(bn + grow) * DDIM + kblk * 8;
  const int ldso = w * 16 * 32;  // wave-uniform LDS base (u16), + c*128*32

  // --- reads: frag row base + r15, k-slot kb; phys slot = kb ^ ((r15>>1)&3)
  const int r15 = lane & 15, kb = lane >> 4;
  const int sphys = (kb ^ ((r15 >> 1) & 3)) * 8;

  f32x4 acc[8][4] = {};

  // prologue: stage tile 0 into buf 0
#pragma unroll
  for (int c = 0; c < 2; ++c) {
    const size_t go = (size_t)c * 128 * DDIM;
    const int lo = ldso + c * 128 * 32;
    GLD16(gAh + go, &smem[0][0][lo]);
    GLD16(gAl + go, &smem[0][1][lo]);
    GLD16(gBh + go, &smem[0][2][lo]);
    GLD16(gBl + go, &smem[0][3][lo]);
  }
  asm volatile("s_waitcnt vmcnt(0)" ::: "memory");
  __builtin_amdgcn_s_barrier();

  for (int t = 0; t < 128; ++t) {
    const u16* br = &smem[t & 1][0][0];
    u16* bw = &smem[(t + 1) & 1][0][0];
    if (t < 127) {  // stage tile t+1 (uniform branch)
      const int k0n = (t + 1) * 32;
#pragma unroll
      for (int c = 0; c < 2; ++c) {
        const size_t go = (size_t)c * 128 * DDIM + k0n;
        const int lo = ldso + c * 128 * 32;
        GLD16(gAh + go, bw + 0 * 8192 + lo);
        GLD16(gAl + go, bw + 1 * 8192 + lo);
        GLD16(gBh + go, bw + 2 * 8192 + lo);
        GLD16(gBl + go, bw + 3 * 8192 + lo);
      }
    }
    // 2 m-halves: A-frags read once each; B rolling-prefetch (re-read per half)
#pragma unroll
    for (int mh = 0; mh < 2; ++mh) {
      short8 xah[4], xal[4], xbh[4], xbl[4];
#pragma unroll
      for (int mi = 0; mi < 4; ++mi) {
        const int row = wm * 128 + mh * 64 + mi * 16 + r15;
        xah[mi] = *(const short8*)(br + 0 * 8192 + row * 32 + sphys);
        xal[mi] = *(const short8*)(br + 1 * 8192 + row * 32 + sphys);
      }
      {
        const int row = wn * 64 + r15;
        xbh[0] = *(const short8*)(br + 2 * 8192 + row * 32 + sphys);
        xbl[0] = *(const short8*)(br + 3 * 8192 + row * 32 + sphys);
      }
      __builtin_amdgcn_s_setprio(1);
#pragma unroll
      for (int ni = 0; ni < 4; ++ni) {
        if (ni < 3) {  // prefetch next B pair; overlaps this ni's 12 MFMAs
          const int row = wn * 64 + (ni + 1) * 16 + r15;
          xbh[ni + 1] = *(const short8*)(br + 2 * 8192 + row * 32 + sphys);
          xbl[ni + 1] = *(const short8*)(br + 3 * 8192 + row * 32 + sphys);
        }
#pragma unroll
        for (int mi = 0; mi < 4; ++mi) {
          f32x4& a = acc[mh * 4 + mi][ni];
          a = __builtin_amdgcn_mfma_f32_16x16x32_bf16(xah[mi], xbh[ni], a, 0, 0, 0);
          a = __builtin_amdgcn_mfma_f32_16x16x32_bf16(xah[mi], xbl[ni], a, 0, 0, 0);
          a = __builtin_amdgcn_mfma_f32_16x16x32_bf16(xal[mi], xbh[ni], a, 0, 0, 0);
        }
      }
      __builtin_amdgcn_s_setprio(0);
    }
    asm volatile("s_waitcnt vmcnt(0)" ::: "memory");  // tile t+1 landed
    __builtin_amdgcn_s_barrier();
  }

  // epilogue: D map (m89): col = lane&15, row = (lane>>4)*4 + q
  const int orow = bm + wm * 128 + kb * 4;
  const int ocol = bn + wn * 64 + r15;
#pragma unroll
  for (int mi = 0; mi < 8; ++mi)
#pragma unroll
    for (int ni = 0; ni < 4; ++ni)
#pragma unroll
      for (int q = 0; q < 4; ++q) {
        const size_t row = (size_t)(orow + mi * 16 + q);
        const size_t col = (size_t)(ocol + ni * 16);
        const size_t o = row * DDIM + col;
        float v = acc[mi][ni][q];
        if (EPI == 0) {
          Cf[o] = v * scale;
        } else if (EPI == 1) {
          u16 h = f2bf(v);
          Ch[o] = h;
          Cl[o] = f2bf(v - bf2f(h));
        } else if (EPI == 2) {
          v += bias[col];
          v = 0.5f * v * (1.0f + erff(v * 0.70710678118654752f));
          u16 h = f2bf(v);
          Ch[o] = h;
          Cl[o] = f2bf(v - bf2f(h));
        } else {
          v += bias[col] + bf2f(Rh[o]) + bf2f(Rl[o]);
          Cf[o] = v;
        }
      }
}

// ---------------------------------------------------------------------------
// Latent attention, fp32 in (xq), bf16-pair out. grid (SEQ/64, NH), 4 waves.
// ---------------------------------------------------------------------------
__global__ __launch_bounds__(256) void attn_k(const float* __restrict__ xq,
                                              const float* __restrict__ kvl,
                                              u16* __restrict__ oh,
                                              u16* __restrict__ ol) {
  __shared__ float kv_s[RLAT * 129];
  __shared__ float xrow[4][DH];
  __shared__ float pbuf[4][RLAT];

  const int h = blockIdx.y;
  const int s0 = blockIdx.x * 64;
  const int tid = threadIdx.x;

#pragma unroll
  for (int i = 0; i < 32; ++i) {
    int idx = i * 256 + tid;
    int r = idx >> 7, d = idx & 127;
    kv_s[r * 129 + d] = kvl[(size_t)r * DDIM + h * DH + d];
  }
  __syncthreads();

  const int wave = tid >> 6;
  const int lane = tid & 63;

  for (int it = 0; it < 16; ++it) {
    const int s = s0 + wave * 16 + it;
    const size_t base = (size_t)s * DDIM + h * DH;
    xrow[wave][lane] = xq[base + lane];
    xrow[wave][lane + 64] = xq[base + lane + 64];

    float sc = 0.f;
    const float* kr = &kv_s[lane * 129];
#pragma unroll 8
    for (int d = 0; d < DH; ++d) sc = fmaf(xrow[wave][d], kr[d], sc);

    float mx = sc;
#pragma unroll
    for (int off = 32; off; off >>= 1) mx = fmaxf(mx, __shfl_xor(mx, off));
    float p = expf(sc - mx);
    float sm = p;
#pragma unroll
    for (int off = 32; off; off >>= 1) sm += __shfl_xor(sm, off);
    p /= sm;
    pbuf[wave][lane] = p;

    float a0 = 0.f, a1 = 0.f;
#pragma unroll 8
    for (int r = 0; r < RLAT; ++r) {
      float pv = pbuf[wave][r];
      a0 = fmaf(pv, kv_s[r * 129 + lane], a0);
      a1 = fmaf(pv, kv_s[r * 129 + lane + 64], a1);
    }
    u16 h0 = f2bf(a0);
    oh[base + lane] = h0;
    ol[base + lane] = f2bf(a0 - bf2f(h0));
    u16 h1 = f2bf(a1);
    oh[base + lane + 64] = h1;
    ol[base + lane + 64] = f2bf(a1 - bf2f(h1));
  }
}

// ---------------------------------------------------------------------------
// fp32 -> (hi,lo) bf16 pair, elementwise (for query)
// ---------------------------------------------------------------------------
__global__ __launch_bounds__(256) void conv_split(const float* __restrict__ in,
                                                  u16* __restrict__ oh,
                                                  u16* __restrict__ ol,
                                                  long n4) {
  long i = (long)blockIdx.x * blockDim.x + threadIdx.x;
  const long stride = (long)gridDim.x * blockDim.x;
  for (; i < n4; i += stride) {
    float4 v = ((const float4*)in)[i];
    u16 h0 = f2bf(v.x), h1 = f2bf(v.y), h2 = f2bf(v.z), h3 = f2bf(v.w);
    u16 l0 = f2bf(v.x - bf2f(h0)), l1 = f2bf(v.y - bf2f(h1));
    u16 l2 = f2bf(v.z - bf2f(h2)), l3 = f2bf(v.w - bf2f(h3));
    uint2 hp, lp;
    hp.x = (uint)h0 | ((uint)h1 << 16);
    hp.y = (uint)h2 | ((uint)h3 << 16);
    lp.x = (uint)l0 | ((uint)l1 << 16);
    lp.y = (uint)l2 | ((uint)l3 << 16);
    ((uint2*)oh)[i] = hp;
    ((uint2*)ol)[i] = lp;
  }
}

// ---------------------------------------------------------------------------
// weight fp32 [K][N] -> transposed bf16 pair [N][K]. 64x64 tiles, grid 4096.
// ---------------------------------------------------------------------------
__global__ __launch_bounds__(256) void conv_wT(const float* __restrict__ w,
                                               u16* __restrict__ oh,
                                               u16* __restrict__ ol) {
  __shared__ float t[64][65];
  const int kb = blockIdx.x & 63, nb = blockIdx.x >> 6;
  const int tid = threadIdx.x;
#pragma unroll
  for (int j = 0; j < 16; ++j) {
    int idx = j * 256 + tid;
    int r = idx >> 6, c = idx & 63;
    t[r][c] = w[(size_t)(kb * 64 + r) * DDIM + nb * 64 + c];
  }
  __syncthreads();
#pragma unroll
  for (int j = 0; j < 16; ++j) {
    int idx = j * 256 + tid;
    int r = idx >> 6, c = idx & 63;  // out: row = n, col = k
    float v = t[c][r];
    u16 h = f2bf(v);
    size_t o = (size_t)(nb * 64 + r) * DDIM + kb * 64 + c;
    oh[o] = h;
    ol[o] = f2bf(v - bf2f(h));
  }
}

extern "C" void kernel_launch(void* const* d_in, const int* in_sizes, int n_in,
                              void* d_out, int out_size, void* d_ws, size_t ws_size,
                              hipStream_t stream) {
  const float* query = (const float*)d_in[0];
  const float* kvl   = (const float*)d_in[1];
  const float* wq    = (const float*)d_in[2];
  const float* wo    = (const float*)d_in[3];
  const float* w1    = (const float*)d_in[4];
  const float* b1    = (const float*)d_in[5];
  const float* w2    = (const float*)d_in[6];
  const float* b2    = (const float*)d_in[7];
  float* out = (float*)d_out;

  char* ws = (char*)d_ws;
  const size_t HB = (size_t)SEQ * DDIM * sizeof(u16);  // 128 MB (one bf16 act matrix)
  const size_t WB = (size_t)DDIM * DDIM * sizeof(u16); // 32 MB  (one bf16 weight)

  // R0 (256MB): q pair -> attn-out pair -> h pair
  u16* qh  = (u16*)(ws);
  u16* ql  = (u16*)(ws + HB);
  u16* ath = qh;  u16* atl = ql;   // after GEMM1
  u16* hh  = qh;  u16* hl  = ql;   // after GEMM2/3
  // R1 (256MB): xq fp32 -> out2 pair
  float* xqf = (float*)(ws + 2 * HB);
  u16* o2h = (u16*)(ws + 2 * HB);
  u16* o2l = (u16*)(ws + 3 * HB);
  // R2 (256MB): weight pairs (transposed)
  char* wr = ws + 4 * HB;
  u16* wqh = (u16*)(wr + 0 * WB); u16* wql = (u16*)(wr + 1 * WB);
  u16* woh = (u16*)(wr + 2 * WB); u16* wol = (u16*)(wr + 3 * WB);
  u16* w1h = (u16*)(wr + 4 * WB); u16* w1l = (u16*)(wr + 5 * WB);
  u16* w2h = (u16*)(wr + 6 * WB); u16* w2l = (u16*)(wr + 7 * WB);

  const long n4 = (long)SEQ * DDIM / 4;
  conv_split<<<8192, 256, 0, stream>>>(query, qh, ql, n4);
  conv_wT<<<4096, 256, 0, stream>>>(wq, wqh, wql);
  conv_wT<<<4096, 256, 0, stream>>>(wo, woh, wol);
  conv_wT<<<4096, 256, 0, stream>>>(w1, w1h, w1l);
  conv_wT<<<4096, 256, 0, stream>>>(w2, w2h, w2l);

  const dim3 gg(1024), gb(512);  // 64 x 16 panels of 256x256
  // xq = (q @ wq) * R^-0.5   (fp32 out for attention)
  gemm_split<0><<<gg, gb, 0, stream>>>(qh, ql, wqh, wql, xqf, nullptr, nullptr,
                                       nullptr, nullptr, nullptr, 0.125f);
  // attention -> pair
  attn_k<<<dim3(SEQ / 64, NH), 256, 0, stream>>>(xqf, kvl, ath, atl);
  // out2 = attn @ wo -> pair only (residual reconstructed later as hi+lo)
  gemm_split<1><<<gg, gb, 0, stream>>>(ath, atl, woh, wol, nullptr, o2h, o2l,
                                       nullptr, nullptr, nullptr, 1.f);
  // h = gelu(out2 @ w1 + b1) -> pair
  gemm_split<2><<<gg, gb, 0, stream>>>(o2h, o2l, w1h, w1l, nullptr, hh, hl,
                                       b1, nullptr, nullptr, 1.f);
  // out = h @ w2 + b2 + out2   (fp32)
  gemm_split<3><<<gg, gb, 0, stream>>>(hh, hl, w2h, w2l, out, nullptr, nullptr,
                                       b2, o2h, o2l, 1.f);
}